// Round 13
// baseline (322.235 us; speedup 1.0000x reference)
//
#include <hip/hip_runtime.h>

#define B_ 2
#define L_ 2048
#define HEADS_ 16
#define DH_ 64
#define DM_ 1024
#define DBI_ 2048
#define DPROJ_ 7168
#define NTOK (B_*L_)      // 4096
#define DCAT (DM_ + DBI_) // 3072

typedef __bf16 bf16;
typedef __attribute__((ext_vector_type(8))) __bf16 bf16x8;
typedef __attribute__((ext_vector_type(4))) __bf16 bf16x4;
typedef __attribute__((ext_vector_type(4))) float floatx4;

typedef __attribute__((address_space(1))) const void gptr_t;
typedef __attribute__((address_space(3))) void lptr_t;

__device__ __forceinline__ void g2l16(const void* g, void* l) {
    __builtin_amdgcn_global_load_lds((gptr_t*)g, (lptr_t*)l, 16, 0, 0);
}

// ---------------- prep: fused weight transposes + in-LN/token-shift ----------------
// r13: transpose_both (10240 blocks) and ln_shift (4096 blocks) are both input-only
// -> one launch, blocks co-scheduled (saves a gap + overlaps the two stages).
__global__ __launch_bounds__(256) void prep(const float* __restrict__ w_in,
                                            const float* __restrict__ w_out,
                                            bf16* __restrict__ w_inT,
                                            bf16* __restrict__ w_outT,
                                            const float* __restrict__ x,
                                            const float* __restrict__ in_g,
                                            const float* __restrict__ in_b,
                                            bf16* __restrict__ xs) {
    int l = blockIdx.x;
    if (l < 10240) {
        __shared__ float tile[32][33];
        const float* in; bf16* outp; int R, C, bx, by;
        if (l < 7168) { in = w_in;  outp = w_inT;  R = DM_;  C = DPROJ_; bx = l % 224; by = l / 224; }
        else { l -= 7168; in = w_out; outp = w_outT; R = DCAT; C = DM_;   bx = l % 32;  by = l / 32; }
        int c0 = bx * 32, r0 = by * 32;
        int x_ = threadIdx.x & 31, y = threadIdx.x >> 5;
        for (int i = 0; i < 32; i += 8)
            tile[y + i][x_] = in[(size_t)(r0 + y + i) * C + (c0 + x_)];
        __syncthreads();
        for (int i = 0; i < 32; i += 8)
            outp[(size_t)(c0 + y + i) * R + (r0 + x_)] = (bf16)tile[x_][y + i];
        return;
    }
    int tok = l - 10240;
    int b = tok / L_, ll = tok % L_;
    int t = threadIdx.x;
    floatx4 v = *(const floatx4*)(x + (size_t)tok * DM_ + t * 4);
    float s = v[0] + v[1] + v[2] + v[3];
    float s2 = v[0]*v[0] + v[1]*v[1] + v[2]*v[2] + v[3]*v[3];
    __shared__ float red[2][4];
    for (int o = 32; o; o >>= 1) { s += __shfl_xor(s, o); s2 += __shfl_xor(s2, o); }
    int w = t >> 6;
    if ((t & 63) == 0) { red[0][w] = s; red[1][w] = s2; }
    __syncthreads();
    s  = red[0][0] + red[0][1] + red[0][2] + red[0][3];
    s2 = red[1][0] + red[1][1] + red[1][2] + red[1][3];
    float mean = s * (1.f / DM_);
    float var  = s2 * (1.f / DM_) - mean * mean;
    float rstd = rsqrtf(var + 1e-5f);
    int c0 = t * 4;
    floatx4 gg = *(const floatx4*)(in_g + c0);
    floatx4 bv = *(const floatx4*)(in_b + c0);
    bf16x4 y;
    #pragma unroll
    for (int i = 0; i < 4; i++) y[i] = (bf16)((v[i] - mean) * rstd * gg[i] + bv[i]);
    int shift = (c0 < 256) ? 1 : ((c0 >= 896) ? 2 : 0);
    int dl = ll + shift;
    if (dl < L_) *(bf16x4*)(xs + ((size_t)b * L_ + dl) * DM_ + c0) = y;
    if (ll == 0 && shift) {
        bf16x4 z = {};
        *(bf16x4*)(xs + ((size_t)b * L_ + 0) * DM_ + c0) = z;
        if (shift == 2) *(bf16x4*)(xs + ((size_t)b * L_ + 1) * DM_ + c0) = z;
    }
}

// ---------------- GEMM1: 256x256, BK=64, 8-wave FREE-RUN: 1 barrier per K-tile ----------------
// r2 best (76us, MfmaUtil 31%).  Locked.
__global__ __launch_bounds__(512, 2) void gemm1_fr(const bf16* __restrict__ A,
                                                   const bf16* __restrict__ Bt,
                                                   bf16* __restrict__ C) {
    const int K = DM_, N = DPROJ_;
    int lin = blockIdx.x;
    int xcd = lin & 7, idx = lin >> 3;            // idx 0..55
    int mt = (xcd >> 2) * 8 + idx / 7;            // 0..15
    int nt = (xcd & 3) * 7 + idx % 7;             // 0..27
    int m0 = mt * 256, n0 = nt * 256;

    __shared__ bf16 As[2][256 * 64];
    __shared__ bf16 Bs[2][256 * 64];

    int t = threadIdx.x;
    int lane = t & 63;
    int c = lane & 15, quad = lane >> 4;
    int wave = t >> 6;
    int wm = (wave >> 2) * 128;
    int wn = (wave & 3) * 64;

    auto stageA = [&](int k0, int bsel, int h) {
        #pragma unroll
        for (int s = 0; s < 2; s++) {
            int g = h * 1024 + s * 512 + t;
            int row = g >> 3;
            int kc = (g & 7) ^ (row & 7);
            g2l16(A + (size_t)(m0 + row) * K + (k0 + kc * 8), &As[bsel][g * 8]);
        }
    };
    auto stageB = [&](int k0, int bsel, int h) {
        #pragma unroll
        for (int s = 0; s < 2; s++) {
            int g = h * 1024 + s * 512 + t;
            int row = g >> 3;
            int kc = (g & 7) ^ (row & 7);
            g2l16(Bt + (size_t)(n0 + row) * K + (k0 + kc * 8), &Bs[bsel][g * 8]);
        }
    };

    floatx4 acc[8][4] = {};

    stageA(0, 0, 0); stageA(0, 0, 1);
    stageB(0, 0, 0); stageB(0, 0, 1);
    stageB(64, 1, 0); stageB(64, 1, 1);
    asm volatile("s_waitcnt vmcnt(4)" ::: "memory");
    __builtin_amdgcn_s_barrier();
    __builtin_amdgcn_sched_barrier(0);

    const int nT = K / 64;
    for (int tt = 0; tt < nT; ++tt) {
        int cur = tt & 1, nxt = cur ^ 1;
        int k1 = (tt + 1) << 6, k2 = (tt + 2) << 6;
        bool dA = (tt + 1 < nT), dB = (tt + 2 < nT);
        bf16x8 bfr[4][2];
        #pragma unroll
        for (int p = 0; p < 4; p++) {
            if      (p == 0) { if (dA) stageA(k1, nxt, 0); }
            else if (p == 1) { if (dA) stageA(k1, nxt, 1); }
            else if (p == 2) { if (dB) stageB(k2, cur, 0); }
            else             { if (dB) stageB(k2, cur, 1); }
            if (p == 0) {
                #pragma unroll
                for (int j = 0; j < 4; j++)
                    #pragma unroll
                    for (int s = 0; s < 2; s++)
                        bfr[j][s] = *(const bf16x8*)&Bs[cur][(wn + j * 16 + c) * 64
                                                            + (((s * 4 + quad) ^ (c & 7)) * 8)];
            }
            bf16x8 af[2][2];
            #pragma unroll
            for (int ii = 0; ii < 2; ii++)
                #pragma unroll
                for (int s = 0; s < 2; s++)
                    af[ii][s] = *(const bf16x8*)&As[cur][(wm + (p * 2 + ii) * 16 + c) * 64
                                                         + (((s * 4 + quad) ^ (c & 7)) * 8)];
            __builtin_amdgcn_s_setprio(1);
            #pragma unroll
            for (int ii = 0; ii < 2; ii++)
                #pragma unroll
                for (int j = 0; j < 4; j++)
                    #pragma unroll
                    for (int s = 0; s < 2; s++)
                        acc[p * 2 + ii][j] = __builtin_amdgcn_mfma_f32_16x16x32_bf16(
                            af[ii][s], bfr[j][s], acc[p * 2 + ii][j], 0, 0, 0);
            __builtin_amdgcn_s_setprio(0);
        }
        asm volatile("s_waitcnt lgkmcnt(0)" ::: "memory");
        if (dB)      { asm volatile("s_waitcnt vmcnt(4)" ::: "memory"); }
        else if (dA) { asm volatile("s_waitcnt vmcnt(0)" ::: "memory"); }
        if (tt + 1 < nT) __builtin_amdgcn_s_barrier();
        __builtin_amdgcn_sched_barrier(0);
    }

    #pragma unroll
    for (int i = 0; i < 8; i++)
        #pragma unroll
        for (int j = 0; j < 4; j++)
            #pragma unroll
            for (int r = 0; r < 4; r++) {
                int row = m0 + wm + i * 16 + quad * 4 + r;
                int col = n0 + wn + j * 16 + c;
                C[(size_t)row * N + col] = (bf16)acc[i][j][r];
            }
}

// ---------------- GEMM2 v3: 128x256, 8 waves, split-K=2, 3-slot B ring (r12 proven) ----------------
__global__ __launch_bounds__(512, 1) void gemm2_fr3(const bf16* __restrict__ A,
                                                    const bf16* __restrict__ Bt,
                                                    float* __restrict__ P) {
    const int ldA = DCAT, N = DM_;
    int m0 = blockIdx.x * 128, n0 = blockIdx.y * 256, kz = blockIdx.z;
    const bf16* Ak = A + kz * 1536;
    const bf16* Btk = Bt + kz * 1536;
    float* C = P + (size_t)kz * NTOK * DM_;
    __shared__ bf16 As[2][128 * 64];   // 2 x 16KB
    __shared__ bf16 Bs[3][256 * 64];   // 3 x 32KB -> 128KB total
    int t = threadIdx.x, lane = t & 63, wave = t >> 6;
    int c = lane & 15, quad = lane >> 4;
    int wm = (wave >> 2) * 64;         // 0 or 64
    int wn = (wave & 3) * 64;          // 0..192

    auto stageA = [&](int k0, int bsel) {
        #pragma unroll
        for (int s = 0; s < 2; s++) {
            int g = s * 512 + t;
            int row = g >> 3;
            int kc = (g & 7) ^ (row & 7);
            g2l16(Ak + (size_t)(m0 + row) * ldA + k0 + kc * 8, &As[bsel][g * 8]);
        }
    };
    auto stageB = [&](int k0, int bsel, int h) {
        #pragma unroll
        for (int s = 0; s < 2; s++) {
            int g = h * 1024 + s * 512 + t;
            int row = g >> 3;
            int kc = (g & 7) ^ (row & 7);
            g2l16(Btk + (size_t)(n0 + row) * ldA + k0 + kc * 8, &Bs[bsel][g * 8]);
        }
    };

    floatx4 acc[4][4] = {};

    stageA(0, 0);
    stageB(0, 0, 0); stageB(0, 0, 1);
    stageB(64, 1, 0); stageB(64, 1, 1);
    asm volatile("s_waitcnt vmcnt(4)" ::: "memory");
    __builtin_amdgcn_s_barrier();
    __builtin_amdgcn_sched_barrier(0);

    const int nT = 1536 / 64;          // 24 K-tiles
    int cb = 0, sb = 2;                // B read slot = tt%3, stage slot = (tt+2)%3
    for (int tt = 0; tt < nT; ++tt) {
        int ca = tt & 1, na = ca ^ 1;
        int k1 = (tt + 1) << 6, k2 = (tt + 2) << 6;
        bool dA = (tt + 1 < nT), dB = (tt + 2 < nT);
        bf16x8 bfr[4][2];
        #pragma unroll
        for (int p = 0; p < 4; p++) {
            if      (p == 0) { if (dA) stageA(k1, na); }
            else if (p == 1) { if (dB) stageB(k2, sb, 0); }
            else if (p == 2) { if (dB) stageB(k2, sb, 1); }
            if (p == 0) {
                #pragma unroll
                for (int j = 0; j < 4; j++)
                    #pragma unroll
                    for (int s = 0; s < 2; s++)
                        bfr[j][s] = *(const bf16x8*)&Bs[cb][(wn + j * 16 + c) * 64
                                                           + (((s * 4 + quad) ^ (c & 7)) * 8)];
            }
            bf16x8 af[2];
            #pragma unroll
            for (int s = 0; s < 2; s++)
                af[s] = *(const bf16x8*)&As[ca][(wm + p * 16 + c) * 64
                                                + (((s * 4 + quad) ^ (c & 7)) * 8)];
            __builtin_amdgcn_s_setprio(1);
            #pragma unroll
            for (int j = 0; j < 4; j++)
                #pragma unroll
                for (int s = 0; s < 2; s++)
                    acc[p][j] = __builtin_amdgcn_mfma_f32_16x16x32_bf16(
                        af[s], bfr[j][s], acc[p][j], 0, 0, 0);
            __builtin_amdgcn_s_setprio(0);
        }
        asm volatile("s_waitcnt lgkmcnt(0)" ::: "memory");
        if (dB)      { asm volatile("s_waitcnt vmcnt(4)" ::: "memory"); }
        else if (dA) { asm volatile("s_waitcnt vmcnt(0)" ::: "memory"); }
        if (tt + 1 < nT) __builtin_amdgcn_s_barrier();
        __builtin_amdgcn_sched_barrier(0);
        cb = (cb == 2) ? 0 : cb + 1;
        sb = (sb == 2) ? 0 : sb + 1;
    }

    #pragma unroll
    for (int p = 0; p < 4; p++)
        #pragma unroll
        for (int j = 0; j < 4; j++)
            #pragma unroll
            for (int r = 0; r < 4; r++) {
                int row = m0 + wm + p * 16 + quad * 4 + r;
                int col = n0 + wn + j * 16 + c;
                C[(size_t)row * N + col] = acc[p][j][r];
            }
}

// ---------------- mid-LN fused v3: v1 structure, bf16x4 vectorized (r8 proven) ----------------
__global__ __launch_bounds__(256) void mid_ln_fused(const bf16* __restrict__ h,
                                                    const float* __restrict__ g,
                                                    const float* __restrict__ bb,
                                                    bf16* __restrict__ Qp,
                                                    bf16* __restrict__ Kp,
                                                    bf16* __restrict__ Vn,
                                                    bf16* __restrict__ A2) {
    int tok = blockIdx.x;
    int b = tok >> 11, l = tok & 2047;
    size_t base = (size_t)tok * DPROJ_;
    int t = threadIdx.x;
    float v[28];
    float s = 0.f, s2 = 0.f;
    #pragma unroll
    for (int i = 0; i < 7; i++) {
        bf16x4 r = *(const bf16x4*)(h + base + (size_t)(t + i * 256) * 4);
        #pragma unroll
        for (int k = 0; k < 4; k++) {
            float f = (float)r[k];
            v[i * 4 + k] = f; s += f; s2 += f * f;
        }
    }
    __shared__ float red[2][4];
    for (int o = 32; o; o >>= 1) { s += __shfl_xor(s, o); s2 += __shfl_xor(s2, o); }
    int w = t >> 6;
    if ((t & 63) == 0) { red[0][w] = s; red[1][w] = s2; }
    __syncthreads();
    s  = red[0][0] + red[0][1] + red[0][2] + red[0][3];
    s2 = red[1][0] + red[1][1] + red[1][2] + red[1][3];
    float mean = s * (1.f / DPROJ_);
    float var  = s2 * (1.f / DPROJ_) - mean * mean;
    float rstd = rsqrtf(var + 1e-5f);
    #pragma unroll
    for (int i = 0; i < 7; i++) {
        int C0 = (t + i * 256) * 4;
        floatx4 gg = *(const floatx4*)(g + C0);
        floatx4 bv = *(const floatx4*)(bb + C0);
        #pragma unroll
        for (int k = 0; k < 4; k++)
            v[i * 4 + k] = (v[i * 4 + k] - mean) * rstd * gg[k] + bv[k];
    }
    #pragma unroll
    for (int i = 0; i < 3; i++) {
        int C0 = (t + i * 256) * 4;
        int sec = C0 >> 10, cc = C0 & 1023;
        int hh = cc >> 6, d = cc & 63;
        bf16* dst = (sec == 0) ? Qp : (sec == 1) ? Kp : Vn;
        size_t idx = (((size_t)b * HEADS_ + hh) * L_ + l) * DH_ + d;
        bf16x4 o;
        #pragma unroll
        for (int k = 0; k < 4; k++) o[k] = (bf16)v[i * 4 + k];
        *(bf16x4*)(dst + idx) = o;
    }
    #pragma unroll
    for (int i = 3; i < 5; i++) {
        int off = (t + i * 256) * 4 - 3 * DM_;   // 4t or 4t+1024
        bf16x4 o;
        #pragma unroll
        for (int k = 0; k < 4; k++) o[k] = (bf16)(v[i * 4 + k] * v[(i + 2) * 4 + k]);
        *(bf16x4*)(A2 + (size_t)tok * DCAT + DM_ + off) = o;
    }
}

// ---------------- Vn [b,h,L,64] -> Vt [b,h,64,L] ----------------
__global__ __launch_bounds__(256) void vt_pack(const bf16* __restrict__ Vn,
                                               bf16* __restrict__ Vt) {
    __shared__ bf16 tile[32][33];
    int bh = blockIdx.z;
    const bf16* in = Vn + (size_t)bh * L_ * DH_;
    bf16* out = Vt + (size_t)bh * DH_ * L_;
    int l0 = blockIdx.x * 32, d0 = blockIdx.y * 32;
    int x = threadIdx.x & 31, y = threadIdx.x >> 5;
    for (int i = 0; i < 32; i += 8)
        tile[y + i][x] = in[(size_t)(l0 + y + i) * DH_ + d0 + x];
    __syncthreads();
    for (int i = 0; i < 32; i += 8)
        out[(size_t)(d0 + y + i) * L_ + l0 + x] = tile[x][y + i];
}

// ---------------- flash attention v9: K AND V double-buffered, 1 barrier/iter ----------------
// r12 analysis: attn6/8 ~2000 cyc/iter vs ~350 compute -> stall-dominated.  The V wait
// (vmcnt mid-iter, covered only by QK+softmax) + 2nd barrier were the exposure.  v9:
// stage K(j0+64)+V(j0+64) -> slot^1 at iter start; consume fully-resident slot with NO
// mid-iter wait; single lgkm(0)+vmcnt(0)+barrier at iter end (loads get QK+softmax+PV
// of cover).  Ordering-safe: slot^1 drained by PREVIOUS iter's end-barrier before this
// stage issues (r12 ring lesson).  LDS 41.2KB -> 3 blocks/CU.  Swizzle/Ps unchanged.
__global__ __launch_bounds__(256, 3) void attn9(const bf16* __restrict__ Qp,
                                                const bf16* __restrict__ Kp,
                                                const bf16* __restrict__ Vt,
                                                const float* __restrict__ slopes,
                                                bf16* __restrict__ A2) {
    int hd = blockIdx.y, b = blockIdx.z;
    int lin = blockIdx.x + 32 * blockIdx.y + 512 * blockIdx.z;
    int xr = blockIdx.x;
    int qt = ((lin >> 8) & 1) ? (31 - xr) : xr;
    int q0 = qt * 64;
    int t = threadIdx.x, lane = t & 63, wave = t >> 6;
    int quad = lane >> 4, c = lane & 15;
    __shared__ bf16 Ks[2][64 * 64];
    __shared__ bf16 Vs[2][64 * 64];
    __shared__ bf16 Ps[4][16 * 72];
    int bh = b * HEADS_ + hd;
    const bf16* Qb = Qp + (size_t)bh * L_ * DH_;
    const bf16* Kb = Kp + (size_t)bh * L_ * DH_;
    const bf16* Vb = Vt + (size_t)bh * DH_ * L_;
    const float LOG2E = 1.44269504f;
    float slopeL2 = slopes[hd] * LOG2E;
    const float qscale = 0.125f * LOG2E;

    bf16x8 qf[2];
    int qrow = q0 + wave * 16 + c;
    qf[0] = *(const bf16x8*)(Qb + (size_t)qrow * DH_ + quad * 8);
    qf[1] = *(const bf16x8*)(Qb + (size_t)qrow * DH_ + 32 + quad * 8);
    floatx4 accO[4] = {};
    float lsum[4];
    float mrow[4];
    int i_row0 = q0 + wave * 16 + quad * 4;
    #pragma unroll
    for (int r = 0; r < 4; r++) {
        lsum[r] = 0.f;
        mrow[r] = slopeL2 * (float)(i_row0 + r) + 20.0f;
    }

    auto stageK = [&](int j0, int kb) {
        #pragma unroll
        for (int s = 0; s < 2; s++) {
            int g = s * 256 + t;
            int row = g >> 3;
            int kc = (g & 7) ^ (row & 7);
            g2l16(Kb + (size_t)(j0 + row) * DH_ + kc * 8, &Ks[kb][g * 8]);
        }
    };
    auto stageV = [&](int j0, int kb) {
        #pragma unroll
        for (int s = 0; s < 2; s++) {
            int g = s * 256 + t;
            int row = g >> 3;
            int kc = (g & 7) ^ (row & 7);
            g2l16(Vb + (size_t)row * L_ + j0 + kc * 8, &Vs[kb][g * 8]);
        }
    };

    bf16* pw = &Ps[wave][0];
    bf16* pwr = pw + (quad * 4) * 72 + c;

    stageK(0, 0); stageV(0, 0);
    asm volatile("s_waitcnt vmcnt(0)" ::: "memory");
    __builtin_amdgcn_s_barrier();
    __builtin_amdgcn_sched_barrier(0);

    int kb = 0;
    for (int j0 = 0; j0 <= q0; j0 += 64) {
        bool dK = (j0 + 64 <= q0);
        if (dK) { stageK(j0 + 64, kb ^ 1); stageV(j0 + 64, kb ^ 1); }

        bool diag = (j0 == q0);
        #pragma unroll
        for (int nt = 0; nt < 4; nt++) {
            floatx4 sacc = {};
            bf16x8 kf0 = *(const bf16x8*)&Ks[kb][(nt * 16 + c) * 64 + (((0 + quad) ^ (c & 7)) * 8)];
            bf16x8 kf1 = *(const bf16x8*)&Ks[kb][(nt * 16 + c) * 64 + (((4 + quad) ^ (c & 7)) * 8)];
            sacc = __builtin_amdgcn_mfma_f32_16x16x32_bf16(qf[0], kf0, sacc, 0, 0, 0);
            sacc = __builtin_amdgcn_mfma_f32_16x16x32_bf16(qf[1], kf1, sacc, 0, 0, 0);
            int j = j0 + nt * 16 + c;
            float aj = slopeL2 * (float)j;
            #pragma unroll
            for (int r = 0; r < 4; r++) {
                float p = exp2f(fmaf(sacc[r], qscale, aj) - mrow[r]);
                if (diag) p = (j <= i_row0 + r) ? p : 0.f;
                lsum[r] += p;
                pwr[r * 72 + nt * 16] = (bf16)p;
            }
        }
        bf16x8 pf0 = *(const bf16x8*)&pw[c * 72 + quad * 8];
        bf16x8 pf1 = *(const bf16x8*)&pw[c * 72 + 32 + quad * 8];

        #pragma unroll
        for (int nt = 0; nt < 4; nt++) {
            bf16x8 vf0 = *(const bf16x8*)&Vs[kb][(nt * 16 + c) * 64 + (((0 + quad) ^ (c & 7)) * 8)];
            bf16x8 vf1 = *(const bf16x8*)&Vs[kb][(nt * 16 + c) * 64 + (((4 + quad) ^ (c & 7)) * 8)];
            accO[nt] = __builtin_amdgcn_mfma_f32_16x16x32_bf16(pf0, vf0, accO[nt], 0, 0, 0);
            accO[nt] = __builtin_amdgcn_mfma_f32_16x16x32_bf16(pf1, vf1, accO[nt], 0, 0, 0);
        }
        // single sync point: my LDS reads of slot kb done; prefetch (issued at iter
        // start, covered by QK+softmax+PV) landed; then all waves cross together.
        asm volatile("s_waitcnt lgkmcnt(0)" ::: "memory");
        if (dK) { asm volatile("s_waitcnt vmcnt(0)" ::: "memory"); }
        __builtin_amdgcn_s_barrier();
        __builtin_amdgcn_sched_barrier(0);
        kb ^= 1;
    }
    #pragma unroll
    for (int r = 0; r < 4; r++) {
        float l = lsum[r];
        l += __shfl_xor(l, 1);
        l += __shfl_xor(l, 2);
        l += __shfl_xor(l, 4);
        l += __shfl_xor(l, 8);
        lsum[r] = 1.f / l;
    }
    #pragma unroll
    for (int r = 0; r < 4; r++) {
        size_t orow = (size_t)b * L_ + q0 + wave * 16 + quad * 4 + r;
        #pragma unroll
        for (int nt = 0; nt < 4; nt++)
            A2[orow * DCAT + hd * DH_ + nt * 16 + c] = (bf16)(accO[nt][r] * lsum[r]);
    }
}

// ---------------- out-LN over 2 contiguous split-K partials, float4 ----------------
__global__ __launch_bounds__(256) void out_ln2(const float* __restrict__ P,
                                               const float* __restrict__ g,
                                               const float* __restrict__ bb,
                                               float* __restrict__ out) {
    size_t base = (size_t)blockIdx.x * DM_;
    const size_t stride = (size_t)NTOK * DM_;
    int t = threadIdx.x;
    floatx4 a = *(const floatx4*)(P + base + t * 4);
    floatx4 b4 = *(const floatx4*)(P + base + stride + t * 4);
    floatx4 v;
    #pragma unroll
    for (int i = 0; i < 4; i++) v[i] = a[i] + b4[i];
    float s = v[0] + v[1] + v[2] + v[3];
    float s2 = v[0]*v[0] + v[1]*v[1] + v[2]*v[2] + v[3]*v[3];
    __shared__ float red[2][4];
    for (int o = 32; o; o >>= 1) { s += __shfl_xor(s, o); s2 += __shfl_xor(s2, o); }
    int w = t >> 6;
    if ((t & 63) == 0) { red[0][w] = s; red[1][w] = s2; }
    __syncthreads();
    s  = red[0][0] + red[0][1] + red[0][2] + red[0][3];
    s2 = red[1][0] + red[1][1] + red[1][2] + red[1][3];
    float mean = s * (1.f / DM_);
    float var  = s2 * (1.f / DM_) - mean * mean;
    float rstd = rsqrtf(var + 1e-5f);
    int c0 = t * 4;
    floatx4 gg = *(const floatx4*)(g + c0);
    floatx4 bv = *(const floatx4*)(bb + c0);
    floatx4 o;
    #pragma unroll
    for (int i = 0; i < 4; i++) o[i] = (v[i] - mean) * rstd * gg[i] + bv[i];
    *(floatx4*)(out + base + c0) = o;
}

extern "C" void kernel_launch(void* const* d_in, const int* in_sizes, int n_in,
                              void* d_out, int out_size, void* d_ws, size_t ws_size,
                              hipStream_t stream) {
    const float* x     = (const float*)d_in[0];
    const float* in_g  = (const float*)d_in[1];
    const float* in_b  = (const float*)d_in[2];
    const float* mid_g = (const float*)d_in[3];
    const float* mid_b = (const float*)d_in[4];
    const float* out_g = (const float*)d_in[5];
    const float* out_b = (const float*)d_in[6];
    const float* w_in  = (const float*)d_in[7];
    const float* w_out = (const float*)d_in[8];
    const float* slopes = (const float*)d_in[9];
    float* out = (float*)d_out;

    char* ws = (char*)d_ws;
    size_t off = 0;
    auto alloc = [&](size_t n) { char* p = ws + off; off += (n + 255) & ~(size_t)255; return p; };
    bf16* w_inT  = (bf16*)alloc((size_t)DPROJ_ * DM_ * 2);   // 14.7 MB
    bf16* w_outT = (bf16*)alloc((size_t)DM_ * DCAT * 2);     // 6.3 MB
    bf16* xs     = (bf16*)alloc((size_t)NTOK * DM_ * 2);     // 8.4 MB (reused as Vt)
    bf16* h      = (bf16*)alloc((size_t)NTOK * DPROJ_ * 2);  // 58.7 MB (reused: 2 contig f32 partials)
    bf16* A2     = (bf16*)alloc((size_t)NTOK * DCAT * 2);    // 25.2 MB
    bf16* Qp     = (bf16*)alloc((size_t)NTOK * DM_ * 2);     // 8.4 MB
    bf16* Kp     = (bf16*)alloc((size_t)NTOK * DM_ * 2);     // 8.4 MB
    bf16* Vn     = (bf16*)alloc((size_t)NTOK * DM_ * 2);     // 8.4 MB
    bf16* Vt = xs;            // xs dead after gemm1
    float* P = (float*)h;     // h dead after mid_ln_fused; gemm2 runs after attn (2x16.8MB fits)

    hipLaunchKernelGGL(prep, dim3(10240 + NTOK), dim3(256), 0, stream,
                       w_in, w_out, w_inT, w_outT, x, in_g, in_b, xs);
    hipLaunchKernelGGL(gemm1_fr, dim3(448), dim3(512), 0, stream, xs, w_inT, h);
    hipLaunchKernelGGL(mid_ln_fused, dim3(NTOK), dim3(256), 0, stream, h, mid_g, mid_b,
                       Qp, Kp, Vn, A2);
    hipLaunchKernelGGL(vt_pack, dim3(L_ / 32, DH_ / 32, B_ * HEADS_), dim3(256), 0, stream, Vn, Vt);
    hipLaunchKernelGGL(attn9, dim3(32, HEADS_, B_), dim3(256), 0, stream, Qp, Kp, Vt, slopes, A2);
    hipLaunchKernelGGL(gemm2_fr3, dim3(NTOK / 128, DM_ / 256, 2), dim3(512), 0, stream,
                       A2, w_outT, P);
    hipLaunchKernelGGL(out_ln2, dim3(NTOK), dim3(256), 0, stream, P, out_g, out_b, out);
}

// Round 14
// 295.258 us; speedup vs baseline: 1.0914x; 1.0914x over previous
//
#include <hip/hip_runtime.h>

#define B_ 2
#define L_ 2048
#define HEADS_ 16
#define DH_ 64
#define DM_ 1024
#define DBI_ 2048
#define DPROJ_ 7168
#define NTOK (B_*L_)      // 4096
#define DCAT (DM_ + DBI_) // 3072

typedef __bf16 bf16;
typedef __attribute__((ext_vector_type(8))) __bf16 bf16x8;
typedef __attribute__((ext_vector_type(4))) __bf16 bf16x4;
typedef __attribute__((ext_vector_type(4))) float floatx4;

typedef __attribute__((address_space(1))) const void gptr_t;
typedef __attribute__((address_space(3))) void lptr_t;

__device__ __forceinline__ void g2l16(const void* g, void* l) {
    __builtin_amdgcn_global_load_lds((gptr_t*)g, (lptr_t*)l, 16, 0, 0);
}

// ---------------- prep: fused weight transposes + in-LN/token-shift (r13, kept) ----------------
__global__ __launch_bounds__(256) void prep(const float* __restrict__ w_in,
                                            const float* __restrict__ w_out,
                                            bf16* __restrict__ w_inT,
                                            bf16* __restrict__ w_outT,
                                            const float* __restrict__ x,
                                            const float* __restrict__ in_g,
                                            const float* __restrict__ in_b,
                                            bf16* __restrict__ xs) {
    int l = blockIdx.x;
    if (l < 10240) {
        __shared__ float tile[32][33];
        const float* in; bf16* outp; int R, C, bx, by;
        if (l < 7168) { in = w_in;  outp = w_inT;  R = DM_;  C = DPROJ_; bx = l % 224; by = l / 224; }
        else { l -= 7168; in = w_out; outp = w_outT; R = DCAT; C = DM_;   bx = l % 32;  by = l / 32; }
        int c0 = bx * 32, r0 = by * 32;
        int x_ = threadIdx.x & 31, y = threadIdx.x >> 5;
        for (int i = 0; i < 32; i += 8)
            tile[y + i][x_] = in[(size_t)(r0 + y + i) * C + (c0 + x_)];
        __syncthreads();
        for (int i = 0; i < 32; i += 8)
            outp[(size_t)(c0 + y + i) * R + (r0 + x_)] = (bf16)tile[x_][y + i];
        return;
    }
    int tok = l - 10240;
    int b = tok / L_, ll = tok % L_;
    int t = threadIdx.x;
    floatx4 v = *(const floatx4*)(x + (size_t)tok * DM_ + t * 4);
    float s = v[0] + v[1] + v[2] + v[3];
    float s2 = v[0]*v[0] + v[1]*v[1] + v[2]*v[2] + v[3]*v[3];
    __shared__ float red[2][4];
    for (int o = 32; o; o >>= 1) { s += __shfl_xor(s, o); s2 += __shfl_xor(s2, o); }
    int w = t >> 6;
    if ((t & 63) == 0) { red[0][w] = s; red[1][w] = s2; }
    __syncthreads();
    s  = red[0][0] + red[0][1] + red[0][2] + red[0][3];
    s2 = red[1][0] + red[1][1] + red[1][2] + red[1][3];
    float mean = s * (1.f / DM_);
    float var  = s2 * (1.f / DM_) - mean * mean;
    float rstd = rsqrtf(var + 1e-5f);
    int c0 = t * 4;
    floatx4 gg = *(const floatx4*)(in_g + c0);
    floatx4 bv = *(const floatx4*)(in_b + c0);
    bf16x4 y;
    #pragma unroll
    for (int i = 0; i < 4; i++) y[i] = (bf16)((v[i] - mean) * rstd * gg[i] + bv[i]);
    int shift = (c0 < 256) ? 1 : ((c0 >= 896) ? 2 : 0);
    int dl = ll + shift;
    if (dl < L_) *(bf16x4*)(xs + ((size_t)b * L_ + dl) * DM_ + c0) = y;
    if (ll == 0 && shift) {
        bf16x4 z = {};
        *(bf16x4*)(xs + ((size_t)b * L_ + 0) * DM_ + c0) = z;
        if (shift == 2) *(bf16x4*)(xs + ((size_t)b * L_ + 1) * DM_ + c0) = z;
    }
}

// ---------------- GEMM1: 256x256, BK=64, 8-wave FREE-RUN: 1 barrier per K-tile ----------------
// r2 best (76us, MfmaUtil 31%).  Locked.
__global__ __launch_bounds__(512, 2) void gemm1_fr(const bf16* __restrict__ A,
                                                   const bf16* __restrict__ Bt,
                                                   bf16* __restrict__ C) {
    const int K = DM_, N = DPROJ_;
    int lin = blockIdx.x;
    int xcd = lin & 7, idx = lin >> 3;            // idx 0..55
    int mt = (xcd >> 2) * 8 + idx / 7;            // 0..15
    int nt = (xcd & 3) * 7 + idx % 7;             // 0..27
    int m0 = mt * 256, n0 = nt * 256;

    __shared__ bf16 As[2][256 * 64];
    __shared__ bf16 Bs[2][256 * 64];

    int t = threadIdx.x;
    int lane = t & 63;
    int c = lane & 15, quad = lane >> 4;
    int wave = t >> 6;
    int wm = (wave >> 2) * 128;
    int wn = (wave & 3) * 64;

    auto stageA = [&](int k0, int bsel, int h) {
        #pragma unroll
        for (int s = 0; s < 2; s++) {
            int g = h * 1024 + s * 512 + t;
            int row = g >> 3;
            int kc = (g & 7) ^ (row & 7);
            g2l16(A + (size_t)(m0 + row) * K + (k0 + kc * 8), &As[bsel][g * 8]);
        }
    };
    auto stageB = [&](int k0, int bsel, int h) {
        #pragma unroll
        for (int s = 0; s < 2; s++) {
            int g = h * 1024 + s * 512 + t;
            int row = g >> 3;
            int kc = (g & 7) ^ (row & 7);
            g2l16(Bt + (size_t)(n0 + row) * K + (k0 + kc * 8), &Bs[bsel][g * 8]);
        }
    };

    floatx4 acc[8][4] = {};

    stageA(0, 0, 0); stageA(0, 0, 1);
    stageB(0, 0, 0); stageB(0, 0, 1);
    stageB(64, 1, 0); stageB(64, 1, 1);
    asm volatile("s_waitcnt vmcnt(4)" ::: "memory");
    __builtin_amdgcn_s_barrier();
    __builtin_amdgcn_sched_barrier(0);

    const int nT = K / 64;
    for (int tt = 0; tt < nT; ++tt) {
        int cur = tt & 1, nxt = cur ^ 1;
        int k1 = (tt + 1) << 6, k2 = (tt + 2) << 6;
        bool dA = (tt + 1 < nT), dB = (tt + 2 < nT);
        bf16x8 bfr[4][2];
        #pragma unroll
        for (int p = 0; p < 4; p++) {
            if      (p == 0) { if (dA) stageA(k1, nxt, 0); }
            else if (p == 1) { if (dA) stageA(k1, nxt, 1); }
            else if (p == 2) { if (dB) stageB(k2, cur, 0); }
            else             { if (dB) stageB(k2, cur, 1); }
            if (p == 0) {
                #pragma unroll
                for (int j = 0; j < 4; j++)
                    #pragma unroll
                    for (int s = 0; s < 2; s++)
                        bfr[j][s] = *(const bf16x8*)&Bs[cur][(wn + j * 16 + c) * 64
                                                            + (((s * 4 + quad) ^ (c & 7)) * 8)];
            }
            bf16x8 af[2][2];
            #pragma unroll
            for (int ii = 0; ii < 2; ii++)
                #pragma unroll
                for (int s = 0; s < 2; s++)
                    af[ii][s] = *(const bf16x8*)&As[cur][(wm + (p * 2 + ii) * 16 + c) * 64
                                                         + (((s * 4 + quad) ^ (c & 7)) * 8)];
            __builtin_amdgcn_s_setprio(1);
            #pragma unroll
            for (int ii = 0; ii < 2; ii++)
                #pragma unroll
                for (int j = 0; j < 4; j++)
                    #pragma unroll
                    for (int s = 0; s < 2; s++)
                        acc[p * 2 + ii][j] = __builtin_amdgcn_mfma_f32_16x16x32_bf16(
                            af[ii][s], bfr[j][s], acc[p * 2 + ii][j], 0, 0, 0);
            __builtin_amdgcn_s_setprio(0);
        }
        asm volatile("s_waitcnt lgkmcnt(0)" ::: "memory");
        if (dB)      { asm volatile("s_waitcnt vmcnt(4)" ::: "memory"); }
        else if (dA) { asm volatile("s_waitcnt vmcnt(0)" ::: "memory"); }
        if (tt + 1 < nT) __builtin_amdgcn_s_barrier();
        __builtin_amdgcn_sched_barrier(0);
    }

    #pragma unroll
    for (int i = 0; i < 8; i++)
        #pragma unroll
        for (int j = 0; j < 4; j++)
            #pragma unroll
            for (int r = 0; r < 4; r++) {
                int row = m0 + wm + i * 16 + quad * 4 + r;
                int col = n0 + wn + j * 16 + c;
                C[(size_t)row * N + col] = (bf16)acc[i][j][r];
            }
}

// ---------------- GEMM2 v3: 128x256, 8 waves, split-K=2, 3-slot B ring (r12 proven) ----------------
__global__ __launch_bounds__(512, 1) void gemm2_fr3(const bf16* __restrict__ A,
                                                    const bf16* __restrict__ Bt,
                                                    float* __restrict__ P) {
    const int ldA = DCAT, N = DM_;
    int m0 = blockIdx.x * 128, n0 = blockIdx.y * 256, kz = blockIdx.z;
    const bf16* Ak = A + kz * 1536;
    const bf16* Btk = Bt + kz * 1536;
    float* C = P + (size_t)kz * NTOK * DM_;
    __shared__ bf16 As[2][128 * 64];   // 2 x 16KB
    __shared__ bf16 Bs[3][256 * 64];   // 3 x 32KB -> 128KB total
    int t = threadIdx.x, lane = t & 63, wave = t >> 6;
    int c = lane & 15, quad = lane >> 4;
    int wm = (wave >> 2) * 64;         // 0 or 64
    int wn = (wave & 3) * 64;          // 0..192

    auto stageA = [&](int k0, int bsel) {
        #pragma unroll
        for (int s = 0; s < 2; s++) {
            int g = s * 512 + t;
            int row = g >> 3;
            int kc = (g & 7) ^ (row & 7);
            g2l16(Ak + (size_t)(m0 + row) * ldA + k0 + kc * 8, &As[bsel][g * 8]);
        }
    };
    auto stageB = [&](int k0, int bsel, int h) {
        #pragma unroll
        for (int s = 0; s < 2; s++) {
            int g = h * 1024 + s * 512 + t;
            int row = g >> 3;
            int kc = (g & 7) ^ (row & 7);
            g2l16(Btk + (size_t)(n0 + row) * ldA + k0 + kc * 8, &Bs[bsel][g * 8]);
        }
    };

    floatx4 acc[4][4] = {};

    stageA(0, 0);
    stageB(0, 0, 0); stageB(0, 0, 1);
    stageB(64, 1, 0); stageB(64, 1, 1);
    asm volatile("s_waitcnt vmcnt(4)" ::: "memory");
    __builtin_amdgcn_s_barrier();
    __builtin_amdgcn_sched_barrier(0);

    const int nT = 1536 / 64;          // 24 K-tiles
    int cb = 0, sb = 2;                // B read slot = tt%3, stage slot = (tt+2)%3
    for (int tt = 0; tt < nT; ++tt) {
        int ca = tt & 1, na = ca ^ 1;
        int k1 = (tt + 1) << 6, k2 = (tt + 2) << 6;
        bool dA = (tt + 1 < nT), dB = (tt + 2 < nT);
        bf16x8 bfr[4][2];
        #pragma unroll
        for (int p = 0; p < 4; p++) {
            if      (p == 0) { if (dA) stageA(k1, na); }
            else if (p == 1) { if (dB) stageB(k2, sb, 0); }
            else if (p == 2) { if (dB) stageB(k2, sb, 1); }
            if (p == 0) {
                #pragma unroll
                for (int j = 0; j < 4; j++)
                    #pragma unroll
                    for (int s = 0; s < 2; s++)
                        bfr[j][s] = *(const bf16x8*)&Bs[cb][(wn + j * 16 + c) * 64
                                                           + (((s * 4 + quad) ^ (c & 7)) * 8)];
            }
            bf16x8 af[2];
            #pragma unroll
            for (int s = 0; s < 2; s++)
                af[s] = *(const bf16x8*)&As[ca][(wm + p * 16 + c) * 64
                                                + (((s * 4 + quad) ^ (c & 7)) * 8)];
            __builtin_amdgcn_s_setprio(1);
            #pragma unroll
            for (int j = 0; j < 4; j++)
                #pragma unroll
                for (int s = 0; s < 2; s++)
                    acc[p][j] = __builtin_amdgcn_mfma_f32_16x16x32_bf16(
                        af[s], bfr[j][s], acc[p][j], 0, 0, 0);
            __builtin_amdgcn_s_setprio(0);
        }
        asm volatile("s_waitcnt lgkmcnt(0)" ::: "memory");
        if (dB)      { asm volatile("s_waitcnt vmcnt(4)" ::: "memory"); }
        else if (dA) { asm volatile("s_waitcnt vmcnt(0)" ::: "memory"); }
        if (tt + 1 < nT) __builtin_amdgcn_s_barrier();
        __builtin_amdgcn_sched_barrier(0);
        cb = (cb == 2) ? 0 : cb + 1;
        sb = (sb == 2) ? 0 : sb + 1;
    }

    #pragma unroll
    for (int p = 0; p < 4; p++)
        #pragma unroll
        for (int j = 0; j < 4; j++)
            #pragma unroll
            for (int r = 0; r < 4; r++) {
                int row = m0 + wm + p * 16 + quad * 4 + r;
                int col = n0 + wn + j * 16 + c;
                C[(size_t)row * N + col] = acc[p][j][r];
            }
}

// ---------------- mid-LN fused v3: v1 structure, bf16x4 vectorized (r8 proven) ----------------
__global__ __launch_bounds__(256) void mid_ln_fused(const bf16* __restrict__ h,
                                                    const float* __restrict__ g,
                                                    const float* __restrict__ bb,
                                                    bf16* __restrict__ Qp,
                                                    bf16* __restrict__ Kp,
                                                    bf16* __restrict__ Vn,
                                                    bf16* __restrict__ A2) {
    int tok = blockIdx.x;
    int b = tok >> 11, l = tok & 2047;
    size_t base = (size_t)tok * DPROJ_;
    int t = threadIdx.x;
    float v[28];
    float s = 0.f, s2 = 0.f;
    #pragma unroll
    for (int i = 0; i < 7; i++) {
        bf16x4 r = *(const bf16x4*)(h + base + (size_t)(t + i * 256) * 4);
        #pragma unroll
        for (int k = 0; k < 4; k++) {
            float f = (float)r[k];
            v[i * 4 + k] = f; s += f; s2 += f * f;
        }
    }
    __shared__ float red[2][4];
    for (int o = 32; o; o >>= 1) { s += __shfl_xor(s, o); s2 += __shfl_xor(s2, o); }
    int w = t >> 6;
    if ((t & 63) == 0) { red[0][w] = s; red[1][w] = s2; }
    __syncthreads();
    s  = red[0][0] + red[0][1] + red[0][2] + red[0][3];
    s2 = red[1][0] + red[1][1] + red[1][2] + red[1][3];
    float mean = s * (1.f / DPROJ_);
    float var  = s2 * (1.f / DPROJ_) - mean * mean;
    float rstd = rsqrtf(var + 1e-5f);
    #pragma unroll
    for (int i = 0; i < 7; i++) {
        int C0 = (t + i * 256) * 4;
        floatx4 gg = *(const floatx4*)(g + C0);
        floatx4 bv = *(const floatx4*)(bb + C0);
        #pragma unroll
        for (int k = 0; k < 4; k++)
            v[i * 4 + k] = (v[i * 4 + k] - mean) * rstd * gg[k] + bv[k];
    }
    #pragma unroll
    for (int i = 0; i < 3; i++) {
        int C0 = (t + i * 256) * 4;
        int sec = C0 >> 10, cc = C0 & 1023;
        int hh = cc >> 6, d = cc & 63;
        bf16* dst = (sec == 0) ? Qp : (sec == 1) ? Kp : Vn;
        size_t idx = (((size_t)b * HEADS_ + hh) * L_ + l) * DH_ + d;
        bf16x4 o;
        #pragma unroll
        for (int k = 0; k < 4; k++) o[k] = (bf16)v[i * 4 + k];
        *(bf16x4*)(dst + idx) = o;
    }
    #pragma unroll
    for (int i = 3; i < 5; i++) {
        int off = (t + i * 256) * 4 - 3 * DM_;   // 4t or 4t+1024
        bf16x4 o;
        #pragma unroll
        for (int k = 0; k < 4; k++) o[k] = (bf16)(v[i * 4 + k] * v[(i + 2) * 4 + k]);
        *(bf16x4*)(A2 + (size_t)tok * DCAT + DM_ + off) = o;
    }
}

// ---------------- Vn [b,h,L,64] -> Vt [b,h,64,L] ----------------
__global__ __launch_bounds__(256) void vt_pack(const bf16* __restrict__ Vn,
                                               bf16* __restrict__ Vt) {
    __shared__ bf16 tile[32][33];
    int bh = blockIdx.z;
    const bf16* in = Vn + (size_t)bh * L_ * DH_;
    bf16* out = Vt + (size_t)bh * DH_ * L_;
    int l0 = blockIdx.x * 32, d0 = blockIdx.y * 32;
    int x = threadIdx.x & 31, y = threadIdx.x >> 5;
    for (int i = 0; i < 32; i += 8)
        tile[y + i][x] = in[(size_t)(l0 + y + i) * DH_ + d0 + x];
    __syncthreads();
    for (int i = 0; i < 32; i += 8)
        out[(size_t)(d0 + y + i) * L_ + l0 + x] = tile[x][y + i];
}

// ---------------- flash attention v8 (r12 best): XOR-swizzled K/V, vmcnt(2) V-wait ----------------
// r13 post-mortem: attn9 (K+V dbuf, 1 barrier, 3 blk/CU) regressed 57->80us — the
// end-of-iter vmcnt(0) exposed the full prefetch latency at LOWER occupancy; attn8's
// split waits (V: vmcnt(2) mid-iter partially covered; K: full-iter cover) + 4 blk/CU
// is strictly better.  Reverted and locked.
__global__ __launch_bounds__(256, 4) void attn8(const bf16* __restrict__ Qp,
                                                const bf16* __restrict__ Kp,
                                                const bf16* __restrict__ Vt,
                                                const float* __restrict__ slopes,
                                                bf16* __restrict__ A2) {
    int hd = blockIdx.y, b = blockIdx.z;
    int lin = blockIdx.x + 32 * blockIdx.y + 512 * blockIdx.z;
    int xr = blockIdx.x;
    int qt = ((lin >> 8) & 1) ? (31 - xr) : xr;
    int q0 = qt * 64;
    int t = threadIdx.x, lane = t & 63, wave = t >> 6;
    int quad = lane >> 4, c = lane & 15;
    __shared__ bf16 Ks[2][64 * 64];
    __shared__ bf16 Vs[64 * 64];
    __shared__ bf16 Ps[4][16 * 72];
    int bh = b * HEADS_ + hd;
    const bf16* Qb = Qp + (size_t)bh * L_ * DH_;
    const bf16* Kb = Kp + (size_t)bh * L_ * DH_;
    const bf16* Vb = Vt + (size_t)bh * DH_ * L_;
    const float LOG2E = 1.44269504f;
    float slopeL2 = slopes[hd] * LOG2E;
    const float qscale = 0.125f * LOG2E;

    bf16x8 qf[2];
    int qrow = q0 + wave * 16 + c;
    qf[0] = *(const bf16x8*)(Qb + (size_t)qrow * DH_ + quad * 8);
    qf[1] = *(const bf16x8*)(Qb + (size_t)qrow * DH_ + 32 + quad * 8);
    floatx4 accO[4] = {};
    float lsum[4];
    float mrow[4];
    int i_row0 = q0 + wave * 16 + quad * 4;
    #pragma unroll
    for (int r = 0; r < 4; r++) {
        lsum[r] = 0.f;
        mrow[r] = slopeL2 * (float)(i_row0 + r) + 20.0f;
    }

    auto stageK = [&](int j0, int kb) {
        #pragma unroll
        for (int s = 0; s < 2; s++) {
            int g = s * 256 + t;
            int row = g >> 3;
            int kc = (g & 7) ^ (row & 7);
            g2l16(Kb + (size_t)(j0 + row) * DH_ + kc * 8, &Ks[kb][g * 8]);
        }
    };
    auto stageV = [&](int j0) {
        #pragma unroll
        for (int s = 0; s < 2; s++) {
            int g = s * 256 + t;
            int row = g >> 3;
            int kc = (g & 7) ^ (row & 7);
            g2l16(Vb + (size_t)row * L_ + j0 + kc * 8, &Vs[g * 8]);
        }
    };

    bf16* pw = &Ps[wave][0];
    bf16* pwr = pw + (quad * 4) * 72 + c;

    stageK(0, 0);
    asm volatile("s_waitcnt vmcnt(0)" ::: "memory");
    __builtin_amdgcn_s_barrier();
    __builtin_amdgcn_sched_barrier(0);

    int kb = 0;
    for (int j0 = 0; j0 <= q0; j0 += 64) {
        bool dK = (j0 + 64 <= q0);
        stageV(j0);
        if (dK) stageK(j0 + 64, kb ^ 1);

        bool diag = (j0 == q0);
        #pragma unroll
        for (int nt = 0; nt < 4; nt++) {
            floatx4 sacc = {};
            bf16x8 kf0 = *(const bf16x8*)&Ks[kb][(nt * 16 + c) * 64 + (((0 + quad) ^ (c & 7)) * 8)];
            bf16x8 kf1 = *(const bf16x8*)&Ks[kb][(nt * 16 + c) * 64 + (((4 + quad) ^ (c & 7)) * 8)];
            sacc = __builtin_amdgcn_mfma_f32_16x16x32_bf16(qf[0], kf0, sacc, 0, 0, 0);
            sacc = __builtin_amdgcn_mfma_f32_16x16x32_bf16(qf[1], kf1, sacc, 0, 0, 0);
            int j = j0 + nt * 16 + c;
            float aj = slopeL2 * (float)j;
            #pragma unroll
            for (int r = 0; r < 4; r++) {
                float p = exp2f(fmaf(sacc[r], qscale, aj) - mrow[r]);
                if (diag) p = (j <= i_row0 + r) ? p : 0.f;
                lsum[r] += p;
                pwr[r * 72 + nt * 16] = (bf16)p;
            }
        }
        bf16x8 pf0 = *(const bf16x8*)&pw[c * 72 + quad * 8];
        bf16x8 pf1 = *(const bf16x8*)&pw[c * 72 + 32 + quad * 8];

        if (dK) { asm volatile("s_waitcnt vmcnt(2)" ::: "memory"); }
        else    { asm volatile("s_waitcnt vmcnt(0)" ::: "memory"); }
        __builtin_amdgcn_s_barrier();
        __builtin_amdgcn_sched_barrier(0);

        #pragma unroll
        for (int nt = 0; nt < 4; nt++) {
            bf16x8 vf0 = *(const bf16x8*)&Vs[(nt * 16 + c) * 64 + (((0 + quad) ^ (c & 7)) * 8)];
            bf16x8 vf1 = *(const bf16x8*)&Vs[(nt * 16 + c) * 64 + (((4 + quad) ^ (c & 7)) * 8)];
            accO[nt] = __builtin_amdgcn_mfma_f32_16x16x32_bf16(pf0, vf0, accO[nt], 0, 0, 0);
            accO[nt] = __builtin_amdgcn_mfma_f32_16x16x32_bf16(pf1, vf1, accO[nt], 0, 0, 0);
        }
        asm volatile("s_waitcnt lgkmcnt(0)" ::: "memory");
        __builtin_amdgcn_s_barrier();
        __builtin_amdgcn_sched_barrier(0);
        kb ^= 1;
    }
    #pragma unroll
    for (int r = 0; r < 4; r++) {
        float l = lsum[r];
        l += __shfl_xor(l, 1);
        l += __shfl_xor(l, 2);
        l += __shfl_xor(l, 4);
        l += __shfl_xor(l, 8);
        lsum[r] = 1.f / l;
    }
    #pragma unroll
    for (int r = 0; r < 4; r++) {
        size_t orow = (size_t)b * L_ + q0 + wave * 16 + quad * 4 + r;
        #pragma unroll
        for (int nt = 0; nt < 4; nt++)
            A2[orow * DCAT + hd * DH_ + nt * 16 + c] = (bf16)(accO[nt][r] * lsum[r]);
    }
}

// ---------------- out-LN over 2 contiguous split-K partials, float4 ----------------
__global__ __launch_bounds__(256) void out_ln2(const float* __restrict__ P,
                                               const float* __restrict__ g,
                                               const float* __restrict__ bb,
                                               float* __restrict__ out) {
    size_t base = (size_t)blockIdx.x * DM_;
    const size_t stride = (size_t)NTOK * DM_;
    int t = threadIdx.x;
    floatx4 a = *(const floatx4*)(P + base + t * 4);
    floatx4 b4 = *(const floatx4*)(P + base + stride + t * 4);
    floatx4 v;
    #pragma unroll
    for (int i = 0; i < 4; i++) v[i] = a[i] + b4[i];
    float s = v[0] + v[1] + v[2] + v[3];
    float s2 = v[0]*v[0] + v[1]*v[1] + v[2]*v[2] + v[3]*v[3];
    __shared__ float red[2][4];
    for (int o = 32; o; o >>= 1) { s += __shfl_xor(s, o); s2 += __shfl_xor(s2, o); }
    int w = t >> 6;
    if ((t & 63) == 0) { red[0][w] = s; red[1][w] = s2; }
    __syncthreads();
    s  = red[0][0] + red[0][1] + red[0][2] + red[0][3];
    s2 = red[1][0] + red[1][1] + red[1][2] + red[1][3];
    float mean = s * (1.f / DM_);
    float var  = s2 * (1.f / DM_) - mean * mean;
    float rstd = rsqrtf(var + 1e-5f);
    int c0 = t * 4;
    floatx4 gg = *(const floatx4*)(g + c0);
    floatx4 bv = *(const floatx4*)(bb + c0);
    floatx4 o;
    #pragma unroll
    for (int i = 0; i < 4; i++) o[i] = (v[i] - mean) * rstd * gg[i] + bv[i];
    *(floatx4*)(out + base + c0) = o;
}

extern "C" void kernel_launch(void* const* d_in, const int* in_sizes, int n_in,
                              void* d_out, int out_size, void* d_ws, size_t ws_size,
                              hipStream_t stream) {
    const float* x     = (const float*)d_in[0];
    const float* in_g  = (const float*)d_in[1];
    const float* in_b  = (const float*)d_in[2];
    const float* mid_g = (const float*)d_in[3];
    const float* mid_b = (const float*)d_in[4];
    const float* out_g = (const float*)d_in[5];
    const float* out_b = (const float*)d_in[6];
    const float* w_in  = (const float*)d_in[7];
    const float* w_out = (const float*)d_in[8];
    const float* slopes = (const float*)d_in[9];
    float* out = (float*)d_out;

    char* ws = (char*)d_ws;
    size_t off = 0;
    auto alloc = [&](size_t n) { char* p = ws + off; off += (n + 255) & ~(size_t)255; return p; };
    bf16* w_inT  = (bf16*)alloc((size_t)DPROJ_ * DM_ * 2);   // 14.7 MB
    bf16* w_outT = (bf16*)alloc((size_t)DM_ * DCAT * 2);     // 6.3 MB
    bf16* xs     = (bf16*)alloc((size_t)NTOK * DM_ * 2);     // 8.4 MB (reused as Vt)
    bf16* h      = (bf16*)alloc((size_t)NTOK * DPROJ_ * 2);  // 58.7 MB (reused: 2 contig f32 partials)
    bf16* A2     = (bf16*)alloc((size_t)NTOK * DCAT * 2);    // 25.2 MB
    bf16* Qp     = (bf16*)alloc((size_t)NTOK * DM_ * 2);     // 8.4 MB
    bf16* Kp     = (bf16*)alloc((size_t)NTOK * DM_ * 2);     // 8.4 MB
    bf16* Vn     = (bf16*)alloc((size_t)NTOK * DM_ * 2);     // 8.4 MB
    bf16* Vt = xs;            // xs dead after gemm1
    float* P = (float*)h;     // h dead after mid_ln_fused; gemm2 runs after attn (2x16.8MB fits)

    hipLaunchKernelGGL(prep, dim3(10240 + NTOK), dim3(256), 0, stream,
                       w_in, w_out, w_inT, w_outT, x, in_g, in_b, xs);
    hipLaunchKernelGGL(gemm1_fr, dim3(448), dim3(512), 0, stream, xs, w_inT, h);
    hipLaunchKernelGGL(mid_ln_fused, dim3(NTOK), dim3(256), 0, stream, h, mid_g, mid_b,
                       Qp, Kp, Vn, A2);
    hipLaunchKernelGGL(vt_pack, dim3(L_ / 32, DH_ / 32, B_ * HEADS_), dim3(256), 0, stream, Vn, Vt);
    hipLaunchKernelGGL(attn8, dim3(32, HEADS_, B_), dim3(256), 0, stream, Qp, Kp, Vt, slopes, A2);
    hipLaunchKernelGGL(gemm2_fr3, dim3(NTOK / 128, DM_ / 256, 2), dim3(512), 0, stream,
                       A2, w_outT, P);
    hipLaunchKernelGGL(out_ln2, dim3(NTOK), dim3(256), 0, stream, P, out_g, out_b, out);
}

// Round 15
// 294.549 us; speedup vs baseline: 1.0940x; 1.0024x over previous
//
#include <hip/hip_runtime.h>

#define B_ 2
#define L_ 2048
#define HEADS_ 16
#define DH_ 64
#define DM_ 1024
#define DBI_ 2048
#define DPROJ_ 7168
#define NTOK (B_*L_)      // 4096
#define DCAT (DM_ + DBI_) // 3072

typedef __bf16 bf16;
typedef __attribute__((ext_vector_type(8))) __bf16 bf16x8;
typedef __attribute__((ext_vector_type(4))) __bf16 bf16x4;
typedef __attribute__((ext_vector_type(4))) float floatx4;

typedef __attribute__((address_space(1))) const void gptr_t;
typedef __attribute__((address_space(3))) void lptr_t;

__device__ __forceinline__ void g2l16(const void* g, void* l) {
    __builtin_amdgcn_global_load_lds((gptr_t*)g, (lptr_t*)l, 16, 0, 0);
}

// ---------------- prep: fused weight transposes + in-LN/token-shift (r13, kept) ----------------
__global__ __launch_bounds__(256) void prep(const float* __restrict__ w_in,
                                            const float* __restrict__ w_out,
                                            bf16* __restrict__ w_inT,
                                            bf16* __restrict__ w_outT,
                                            const float* __restrict__ x,
                                            const float* __restrict__ in_g,
                                            const float* __restrict__ in_b,
                                            bf16* __restrict__ xs) {
    int l = blockIdx.x;
    if (l < 10240) {
        __shared__ float tile[32][33];
        const float* in; bf16* outp; int R, C, bx, by;
        if (l < 7168) { in = w_in;  outp = w_inT;  R = DM_;  C = DPROJ_; bx = l % 224; by = l / 224; }
        else { l -= 7168; in = w_out; outp = w_outT; R = DCAT; C = DM_;   bx = l % 32;  by = l / 32; }
        int c0 = bx * 32, r0 = by * 32;
        int x_ = threadIdx.x & 31, y = threadIdx.x >> 5;
        for (int i = 0; i < 32; i += 8)
            tile[y + i][x_] = in[(size_t)(r0 + y + i) * C + (c0 + x_)];
        __syncthreads();
        for (int i = 0; i < 32; i += 8)
            outp[(size_t)(c0 + y + i) * R + (r0 + x_)] = (bf16)tile[x_][y + i];
        return;
    }
    int tok = l - 10240;
    int b = tok / L_, ll = tok % L_;
    int t = threadIdx.x;
    floatx4 v = *(const floatx4*)(x + (size_t)tok * DM_ + t * 4);
    float s = v[0] + v[1] + v[2] + v[3];
    float s2 = v[0]*v[0] + v[1]*v[1] + v[2]*v[2] + v[3]*v[3];
    __shared__ float red[2][4];
    for (int o = 32; o; o >>= 1) { s += __shfl_xor(s, o); s2 += __shfl_xor(s2, o); }
    int w = t >> 6;
    if ((t & 63) == 0) { red[0][w] = s; red[1][w] = s2; }
    __syncthreads();
    s  = red[0][0] + red[0][1] + red[0][2] + red[0][3];
    s2 = red[1][0] + red[1][1] + red[1][2] + red[1][3];
    float mean = s * (1.f / DM_);
    float var  = s2 * (1.f / DM_) - mean * mean;
    float rstd = rsqrtf(var + 1e-5f);
    int c0 = t * 4;
    floatx4 gg = *(const floatx4*)(in_g + c0);
    floatx4 bv = *(const floatx4*)(in_b + c0);
    bf16x4 y;
    #pragma unroll
    for (int i = 0; i < 4; i++) y[i] = (bf16)((v[i] - mean) * rstd * gg[i] + bv[i]);
    int shift = (c0 < 256) ? 1 : ((c0 >= 896) ? 2 : 0);
    int dl = ll + shift;
    if (dl < L_) *(bf16x4*)(xs + ((size_t)b * L_ + dl) * DM_ + c0) = y;
    if (ll == 0 && shift) {
        bf16x4 z = {};
        *(bf16x4*)(xs + ((size_t)b * L_ + 0) * DM_ + c0) = z;
        if (shift == 2) *(bf16x4*)(xs + ((size_t)b * L_ + 1) * DM_ + c0) = z;
    }
}

// ---------------- GEMM1 zero-tail: 256x224 tile, 512 blocks = exactly 2 rounds ----------------
// r14 analysis: 448 tiles over 256 CUs (1 blk/CU) -> makespan 2*T_block with only
// 1.75*256 tiles of work = 12.5% idle-CU tail.  256x224 (14 N-frags) -> 16x32 = 512
// blocks, every CU gets exactly 2 -> makespan 1.75*T_block.  Waves 4Mx2N: per-wave
// 64x112 (acc[4][7]).  B = 3-slot ring (ordering-safe, r11/r12 lesson: 2-buffer
// prefetch-into-read-slot races at short phases).  B staging 1792 chunks = 3.5/thread:
// waves 0-3 carry a 4th chunk; per-wave vmcnt immediates (4 vs 3).  LDS 64+84=148KB.
__global__ __launch_bounds__(512, 1) void gemm1_zt(const bf16* __restrict__ A,
                                                   const bf16* __restrict__ Bt,
                                                   bf16* __restrict__ C) {
    const int K = DM_, N = DPROJ_;
    int lin = blockIdx.x;
    int xcd = lin & 7, idx = lin >> 3;            // idx 0..63
    int mt = (xcd >> 2) * 8 + (idx >> 3);         // 0..15
    int nt = (xcd & 3) * 8 + (idx & 7);           // 0..31
    int m0 = mt * 256, n0 = nt * 224;

    __shared__ bf16 As[2][256 * 64];   // 2 x 32KB
    __shared__ bf16 Bs[3][224 * 64];   // 3 x 28KB -> 148KB total

    int t = threadIdx.x;
    int lane = t & 63;
    int c = lane & 15, quad = lane >> 4;
    int wave = t >> 6;
    int wm = (wave >> 1) * 64;         // 0,64,128,192
    int wn = (wave & 1) * 112;        // 0 or 112

    auto stageA = [&](int k0, int bsel, int h) {
        #pragma unroll
        for (int s = 0; s < 2; s++) {
            int g = h * 1024 + s * 512 + t;
            int row = g >> 3;
            int kc = (g & 7) ^ (row & 7);
            g2l16(A + (size_t)(m0 + row) * K + (k0 + kc * 8), &As[bsel][g * 8]);
        }
    };
    // B: 224 rows x 64 = 1792 chunks.  h0: chunks 0..1023; h1: 1024..1535 (all) +
    // 1536..1791 (waves 0-3 only; wave-uniform branch).
    auto stageB = [&](int k0, int slot, int h) {
        if (h == 0) {
            #pragma unroll
            for (int s = 0; s < 2; s++) {
                int g = s * 512 + t;
                int row = g >> 3;
                int kc = (g & 7) ^ (row & 7);
                g2l16(Bt + (size_t)(n0 + row) * K + (k0 + kc * 8), &Bs[slot][g * 8]);
            }
        } else {
            int g = 1024 + t;
            int row = g >> 3;
            int kc = (g & 7) ^ (row & 7);
            g2l16(Bt + (size_t)(n0 + row) * K + (k0 + kc * 8), &Bs[slot][g * 8]);
            if (wave < 4) {
                int g2 = 1536 + t;
                int row2 = g2 >> 3;
                int kc2 = (g2 & 7) ^ (row2 & 7);
                g2l16(Bt + (size_t)(n0 + row2) * K + (k0 + kc2 * 8), &Bs[slot][g2 * 8]);
            }
        }
    };

    floatx4 acc[4][7] = {};

    // prologue: A0 -> buf0; B0 -> slot0; B1 -> slot1; keep B1 in flight (4 or 3 loads)
    stageA(0, 0, 0); stageA(0, 0, 1);
    stageB(0, 0, 0); stageB(0, 0, 1);
    stageB(64, 1, 0); stageB(64, 1, 1);
    if (wave < 4) { asm volatile("s_waitcnt vmcnt(4)" ::: "memory"); }
    else          { asm volatile("s_waitcnt vmcnt(3)" ::: "memory"); }
    __builtin_amdgcn_s_barrier();
    __builtin_amdgcn_sched_barrier(0);

    const int nT = K / 64;             // 16 K-tiles
    int cb = 0, sb = 2;                // B read slot = tt%3, stage slot = (tt+2)%3
    for (int tt = 0; tt < nT; ++tt) {
        int ca = tt & 1, na = ca ^ 1;
        int k1 = (tt + 1) << 6, k2 = (tt + 2) << 6;
        bool dA = (tt + 1 < nT), dB = (tt + 2 < nT);
        bf16x8 bfr[7][2];
        #pragma unroll
        for (int p = 0; p < 4; p++) {
            if      (p == 0) { if (dA) stageA(k1, na, 0); }
            else if (p == 1) { if (dA) stageA(k1, na, 1); }
            else if (p == 2) { if (dB) stageB(k2, sb, 0); }
            else             { if (dB) stageB(k2, sb, 1); }
            if (p == 0) {
                #pragma unroll
                for (int j = 0; j < 7; j++)
                    #pragma unroll
                    for (int s = 0; s < 2; s++)
                        bfr[j][s] = *(const bf16x8*)&Bs[cb][(wn + j * 16 + c) * 64
                                                           + (((s * 4 + quad) ^ (c & 7)) * 8)];
            }
            bf16x8 af[2];
            #pragma unroll
            for (int s = 0; s < 2; s++)
                af[s] = *(const bf16x8*)&As[ca][(wm + p * 16 + c) * 64
                                                + (((s * 4 + quad) ^ (c & 7)) * 8)];
            __builtin_amdgcn_s_setprio(1);
            #pragma unroll
            for (int j = 0; j < 7; j++)
                #pragma unroll
                for (int s = 0; s < 2; s++)
                    acc[p][j] = __builtin_amdgcn_mfma_f32_16x16x32_bf16(
                        af[s], bfr[j][s], acc[p][j], 0, 0, 0);
            __builtin_amdgcn_s_setprio(0);
        }
        // single sync point per K-tile: only B(tt+2) stays in flight (4 or 3 loads)
        asm volatile("s_waitcnt lgkmcnt(0)" ::: "memory");
        if (dB) {
            if (wave < 4) { asm volatile("s_waitcnt vmcnt(4)" ::: "memory"); }
            else          { asm volatile("s_waitcnt vmcnt(3)" ::: "memory"); }
        } else if (dA) {
            asm volatile("s_waitcnt vmcnt(0)" ::: "memory");
        }
        if (tt + 1 < nT) __builtin_amdgcn_s_barrier();
        __builtin_amdgcn_sched_barrier(0);
        cb = (cb == 2) ? 0 : cb + 1;
        sb = (sb == 2) ? 0 : sb + 1;
    }

    #pragma unroll
    for (int p = 0; p < 4; p++)
        #pragma unroll
        for (int j = 0; j < 7; j++)
            #pragma unroll
            for (int r = 0; r < 4; r++) {
                int row = m0 + wm + p * 16 + quad * 4 + r;
                int col = n0 + wn + j * 16 + c;
                C[(size_t)row * N + col] = (bf16)acc[p][j][r];
            }
}

// ---------------- GEMM2 v3: 128x256, 8 waves, split-K=2, 3-slot B ring (r12 proven) ----------------
__global__ __launch_bounds__(512, 1) void gemm2_fr3(const bf16* __restrict__ A,
                                                    const bf16* __restrict__ Bt,
                                                    float* __restrict__ P) {
    const int ldA = DCAT, N = DM_;
    int m0 = blockIdx.x * 128, n0 = blockIdx.y * 256, kz = blockIdx.z;
    const bf16* Ak = A + kz * 1536;
    const bf16* Btk = Bt + kz * 1536;
    float* C = P + (size_t)kz * NTOK * DM_;
    __shared__ bf16 As[2][128 * 64];   // 2 x 16KB
    __shared__ bf16 Bs[3][256 * 64];   // 3 x 32KB -> 128KB total
    int t = threadIdx.x, lane = t & 63, wave = t >> 6;
    int c = lane & 15, quad = lane >> 4;
    int wm = (wave >> 2) * 64;         // 0 or 64
    int wn = (wave & 3) * 64;          // 0..192

    auto stageA = [&](int k0, int bsel) {
        #pragma unroll
        for (int s = 0; s < 2; s++) {
            int g = s * 512 + t;
            int row = g >> 3;
            int kc = (g & 7) ^ (row & 7);
            g2l16(Ak + (size_t)(m0 + row) * ldA + k0 + kc * 8, &As[bsel][g * 8]);
        }
    };
    auto stageB = [&](int k0, int bsel, int h) {
        #pragma unroll
        for (int s = 0; s < 2; s++) {
            int g = h * 1024 + s * 512 + t;
            int row = g >> 3;
            int kc = (g & 7) ^ (row & 7);
            g2l16(Btk + (size_t)(n0 + row) * ldA + k0 + kc * 8, &Bs[bsel][g * 8]);
        }
    };

    floatx4 acc[4][4] = {};

    stageA(0, 0);
    stageB(0, 0, 0); stageB(0, 0, 1);
    stageB(64, 1, 0); stageB(64, 1, 1);
    asm volatile("s_waitcnt vmcnt(4)" ::: "memory");
    __builtin_amdgcn_s_barrier();
    __builtin_amdgcn_sched_barrier(0);

    const int nT = 1536 / 64;          // 24 K-tiles
    int cb = 0, sb = 2;
    for (int tt = 0; tt < nT; ++tt) {
        int ca = tt & 1, na = ca ^ 1;
        int k1 = (tt + 1) << 6, k2 = (tt + 2) << 6;
        bool dA = (tt + 1 < nT), dB = (tt + 2 < nT);
        bf16x8 bfr[4][2];
        #pragma unroll
        for (int p = 0; p < 4; p++) {
            if      (p == 0) { if (dA) stageA(k1, na); }
            else if (p == 1) { if (dB) stageB(k2, sb, 0); }
            else if (p == 2) { if (dB) stageB(k2, sb, 1); }
            if (p == 0) {
                #pragma unroll
                for (int j = 0; j < 4; j++)
                    #pragma unroll
                    for (int s = 0; s < 2; s++)
                        bfr[j][s] = *(const bf16x8*)&Bs[cb][(wn + j * 16 + c) * 64
                                                           + (((s * 4 + quad) ^ (c & 7)) * 8)];
            }
            bf16x8 af[2];
            #pragma unroll
            for (int s = 0; s < 2; s++)
                af[s] = *(const bf16x8*)&As[ca][(wm + p * 16 + c) * 64
                                                + (((s * 4 + quad) ^ (c & 7)) * 8)];
            __builtin_amdgcn_s_setprio(1);
            #pragma unroll
            for (int j = 0; j < 4; j++)
                #pragma unroll
                for (int s = 0; s < 2; s++)
                    acc[p][j] = __builtin_amdgcn_mfma_f32_16x16x32_bf16(
                        af[s], bfr[j][s], acc[p][j], 0, 0, 0);
            __builtin_amdgcn_s_setprio(0);
        }
        asm volatile("s_waitcnt lgkmcnt(0)" ::: "memory");
        if (dB)      { asm volatile("s_waitcnt vmcnt(4)" ::: "memory"); }
        else if (dA) { asm volatile("s_waitcnt vmcnt(0)" ::: "memory"); }
        if (tt + 1 < nT) __builtin_amdgcn_s_barrier();
        __builtin_amdgcn_sched_barrier(0);
        cb = (cb == 2) ? 0 : cb + 1;
        sb = (sb == 2) ? 0 : sb + 1;
    }

    #pragma unroll
    for (int p = 0; p < 4; p++)
        #pragma unroll
        for (int j = 0; j < 4; j++)
            #pragma unroll
            for (int r = 0; r < 4; r++) {
                int row = m0 + wm + p * 16 + quad * 4 + r;
                int col = n0 + wn + j * 16 + c;
                C[(size_t)row * N + col] = acc[p][j][r];
            }
}

// ---------------- mid-LN fused v3: v1 structure, bf16x4 vectorized (r8 proven) ----------------
__global__ __launch_bounds__(256) void mid_ln_fused(const bf16* __restrict__ h,
                                                    const float* __restrict__ g,
                                                    const float* __restrict__ bb,
                                                    bf16* __restrict__ Qp,
                                                    bf16* __restrict__ Kp,
                                                    bf16* __restrict__ Vn,
                                                    bf16* __restrict__ A2) {
    int tok = blockIdx.x;
    int b = tok >> 11, l = tok & 2047;
    size_t base = (size_t)tok * DPROJ_;
    int t = threadIdx.x;
    float v[28];
    float s = 0.f, s2 = 0.f;
    #pragma unroll
    for (int i = 0; i < 7; i++) {
        bf16x4 r = *(const bf16x4*)(h + base + (size_t)(t + i * 256) * 4);
        #pragma unroll
        for (int k = 0; k < 4; k++) {
            float f = (float)r[k];
            v[i * 4 + k] = f; s += f; s2 += f * f;
        }
    }
    __shared__ float red[2][4];
    for (int o = 32; o; o >>= 1) { s += __shfl_xor(s, o); s2 += __shfl_xor(s2, o); }
    int w = t >> 6;
    if ((t & 63) == 0) { red[0][w] = s; red[1][w] = s2; }
    __syncthreads();
    s  = red[0][0] + red[0][1] + red[0][2] + red[0][3];
    s2 = red[1][0] + red[1][1] + red[1][2] + red[1][3];
    float mean = s * (1.f / DPROJ_);
    float var  = s2 * (1.f / DPROJ_) - mean * mean;
    float rstd = rsqrtf(var + 1e-5f);
    #pragma unroll
    for (int i = 0; i < 7; i++) {
        int C0 = (t + i * 256) * 4;
        floatx4 gg = *(const floatx4*)(g + C0);
        floatx4 bv = *(const floatx4*)(bb + C0);
        #pragma unroll
        for (int k = 0; k < 4; k++)
            v[i * 4 + k] = (v[i * 4 + k] - mean) * rstd * gg[k] + bv[k];
    }
    #pragma unroll
    for (int i = 0; i < 3; i++) {
        int C0 = (t + i * 256) * 4;
        int sec = C0 >> 10, cc = C0 & 1023;
        int hh = cc >> 6, d = cc & 63;
        bf16* dst = (sec == 0) ? Qp : (sec == 1) ? Kp : Vn;
        size_t idx = (((size_t)b * HEADS_ + hh) * L_ + l) * DH_ + d;
        bf16x4 o;
        #pragma unroll
        for (int k = 0; k < 4; k++) o[k] = (bf16)v[i * 4 + k];
        *(bf16x4*)(dst + idx) = o;
    }
    #pragma unroll
    for (int i = 3; i < 5; i++) {
        int off = (t + i * 256) * 4 - 3 * DM_;   // 4t or 4t+1024
        bf16x4 o;
        #pragma unroll
        for (int k = 0; k < 4; k++) o[k] = (bf16)(v[i * 4 + k] * v[(i + 2) * 4 + k]);
        *(bf16x4*)(A2 + (size_t)tok * DCAT + DM_ + off) = o;
    }
}

// ---------------- Vn [b,h,L,64] -> Vt [b,h,64,L] ----------------
__global__ __launch_bounds__(256) void vt_pack(const bf16* __restrict__ Vn,
                                               bf16* __restrict__ Vt) {
    __shared__ bf16 tile[32][33];
    int bh = blockIdx.z;
    const bf16* in = Vn + (size_t)bh * L_ * DH_;
    bf16* out = Vt + (size_t)bh * DH_ * L_;
    int l0 = blockIdx.x * 32, d0 = blockIdx.y * 32;
    int x = threadIdx.x & 31, y = threadIdx.x >> 5;
    for (int i = 0; i < 32; i += 8)
        tile[y + i][x] = in[(size_t)(l0 + y + i) * DH_ + d0 + x];
    __syncthreads();
    for (int i = 0; i < 32; i += 8)
        out[(size_t)(d0 + y + i) * L_ + l0 + x] = tile[x][y + i];
}

// ---------------- flash attention v8 (r12 best, locked) ----------------
__global__ __launch_bounds__(256, 4) void attn8(const bf16* __restrict__ Qp,
                                                const bf16* __restrict__ Kp,
                                                const bf16* __restrict__ Vt,
                                                const float* __restrict__ slopes,
                                                bf16* __restrict__ A2) {
    int hd = blockIdx.y, b = blockIdx.z;
    int lin = blockIdx.x + 32 * blockIdx.y + 512 * blockIdx.z;
    int xr = blockIdx.x;
    int qt = ((lin >> 8) & 1) ? (31 - xr) : xr;
    int q0 = qt * 64;
    int t = threadIdx.x, lane = t & 63, wave = t >> 6;
    int quad = lane >> 4, c = lane & 15;
    __shared__ bf16 Ks[2][64 * 64];
    __shared__ bf16 Vs[64 * 64];
    __shared__ bf16 Ps[4][16 * 72];
    int bh = b * HEADS_ + hd;
    const bf16* Qb = Qp + (size_t)bh * L_ * DH_;
    const bf16* Kb = Kp + (size_t)bh * L_ * DH_;
    const bf16* Vb = Vt + (size_t)bh * DH_ * L_;
    const float LOG2E = 1.44269504f;
    float slopeL2 = slopes[hd] * LOG2E;
    const float qscale = 0.125f * LOG2E;

    bf16x8 qf[2];
    int qrow = q0 + wave * 16 + c;
    qf[0] = *(const bf16x8*)(Qb + (size_t)qrow * DH_ + quad * 8);
    qf[1] = *(const bf16x8*)(Qb + (size_t)qrow * DH_ + 32 + quad * 8);
    floatx4 accO[4] = {};
    float lsum[4];
    float mrow[4];
    int i_row0 = q0 + wave * 16 + quad * 4;
    #pragma unroll
    for (int r = 0; r < 4; r++) {
        lsum[r] = 0.f;
        mrow[r] = slopeL2 * (float)(i_row0 + r) + 20.0f;
    }

    auto stageK = [&](int j0, int kb) {
        #pragma unroll
        for (int s = 0; s < 2; s++) {
            int g = s * 256 + t;
            int row = g >> 3;
            int kc = (g & 7) ^ (row & 7);
            g2l16(Kb + (size_t)(j0 + row) * DH_ + kc * 8, &Ks[kb][g * 8]);
        }
    };
    auto stageV = [&](int j0) {
        #pragma unroll
        for (int s = 0; s < 2; s++) {
            int g = s * 256 + t;
            int row = g >> 3;
            int kc = (g & 7) ^ (row & 7);
            g2l16(Vb + (size_t)row * L_ + j0 + kc * 8, &Vs[g * 8]);
        }
    };

    bf16* pw = &Ps[wave][0];
    bf16* pwr = pw + (quad * 4) * 72 + c;

    stageK(0, 0);
    asm volatile("s_waitcnt vmcnt(0)" ::: "memory");
    __builtin_amdgcn_s_barrier();
    __builtin_amdgcn_sched_barrier(0);

    int kb = 0;
    for (int j0 = 0; j0 <= q0; j0 += 64) {
        bool dK = (j0 + 64 <= q0);
        stageV(j0);
        if (dK) stageK(j0 + 64, kb ^ 1);

        bool diag = (j0 == q0);
        #pragma unroll
        for (int nt = 0; nt < 4; nt++) {
            floatx4 sacc = {};
            bf16x8 kf0 = *(const bf16x8*)&Ks[kb][(nt * 16 + c) * 64 + (((0 + quad) ^ (c & 7)) * 8)];
            bf16x8 kf1 = *(const bf16x8*)&Ks[kb][(nt * 16 + c) * 64 + (((4 + quad) ^ (c & 7)) * 8)];
            sacc = __builtin_amdgcn_mfma_f32_16x16x32_bf16(qf[0], kf0, sacc, 0, 0, 0);
            sacc = __builtin_amdgcn_mfma_f32_16x16x32_bf16(qf[1], kf1, sacc, 0, 0, 0);
            int j = j0 + nt * 16 + c;
            float aj = slopeL2 * (float)j;
            #pragma unroll
            for (int r = 0; r < 4; r++) {
                float p = exp2f(fmaf(sacc[r], qscale, aj) - mrow[r]);
                if (diag) p = (j <= i_row0 + r) ? p : 0.f;
                lsum[r] += p;
                pwr[r * 72 + nt * 16] = (bf16)p;
            }
        }
        bf16x8 pf0 = *(const bf16x8*)&pw[c * 72 + quad * 8];
        bf16x8 pf1 = *(const bf16x8*)&pw[c * 72 + 32 + quad * 8];

        if (dK) { asm volatile("s_waitcnt vmcnt(2)" ::: "memory"); }
        else    { asm volatile("s_waitcnt vmcnt(0)" ::: "memory"); }
        __builtin_amdgcn_s_barrier();
        __builtin_amdgcn_sched_barrier(0);

        #pragma unroll
        for (int nt = 0; nt < 4; nt++) {
            bf16x8 vf0 = *(const bf16x8*)&Vs[(nt * 16 + c) * 64 + (((0 + quad) ^ (c & 7)) * 8)];
            bf16x8 vf1 = *(const bf16x8*)&Vs[(nt * 16 + c) * 64 + (((4 + quad) ^ (c & 7)) * 8)];
            accO[nt] = __builtin_amdgcn_mfma_f32_16x16x32_bf16(pf0, vf0, accO[nt], 0, 0, 0);
            accO[nt] = __builtin_amdgcn_mfma_f32_16x16x32_bf16(pf1, vf1, accO[nt], 0, 0, 0);
        }
        asm volatile("s_waitcnt lgkmcnt(0)" ::: "memory");
        __builtin_amdgcn_s_barrier();
        __builtin_amdgcn_sched_barrier(0);
        kb ^= 1;
    }
    #pragma unroll
    for (int r = 0; r < 4; r++) {
        float l = lsum[r];
        l += __shfl_xor(l, 1);
        l += __shfl_xor(l, 2);
        l += __shfl_xor(l, 4);
        l += __shfl_xor(l, 8);
        lsum[r] = 1.f / l;
    }
    #pragma unroll
    for (int r = 0; r < 4; r++) {
        size_t orow = (size_t)b * L_ + q0 + wave * 16 + quad * 4 + r;
        #pragma unroll
        for (int nt = 0; nt < 4; nt++)
            A2[orow * DCAT + hd * DH_ + nt * 16 + c] = (bf16)(accO[nt][r] * lsum[r]);
    }
}

// ---------------- out-LN over 2 contiguous split-K partials, float4 ----------------
__global__ __launch_bounds__(256) void out_ln2(const float* __restrict__ P,
                                               const float* __restrict__ g,
                                               const float* __restrict__ bb,
                                               float* __restrict__ out) {
    size_t base = (size_t)blockIdx.x * DM_;
    const size_t stride = (size_t)NTOK * DM_;
    int t = threadIdx.x;
    floatx4 a = *(const floatx4*)(P + base + t * 4);
    floatx4 b4 = *(const floatx4*)(P + base + stride + t * 4);
    floatx4 v;
    #pragma unroll
    for (int i = 0; i < 4; i++) v[i] = a[i] + b4[i];
    float s = v[0] + v[1] + v[2] + v[3];
    float s2 = v[0]*v[0] + v[1]*v[1] + v[2]*v[2] + v[3]*v[3];
    __shared__ float red[2][4];
    for (int o = 32; o; o >>= 1) { s += __shfl_xor(s, o); s2 += __shfl_xor(s2, o); }
    int w = t >> 6;
    if ((t & 63) == 0) { red[0][w] = s; red[1][w] = s2; }
    __syncthreads();
    s  = red[0][0] + red[0][1] + red[0][2] + red[0][3];
    s2 = red[1][0] + red[1][1] + red[1][2] + red[1][3];
    float mean = s * (1.f / DM_);
    float var  = s2 * (1.f / DM_) - mean * mean;
    float rstd = rsqrtf(var + 1e-5f);
    int c0 = t * 4;
    floatx4 gg = *(const floatx4*)(g + c0);
    floatx4 bv = *(const floatx4*)(bb + c0);
    floatx4 o;
    #pragma unroll
    for (int i = 0; i < 4; i++) o[i] = (v[i] - mean) * rstd * gg[i] + bv[i];
    *(floatx4*)(out + base + c0) = o;
}

extern "C" void kernel_launch(void* const* d_in, const int* in_sizes, int n_in,
                              void* d_out, int out_size, void* d_ws, size_t ws_size,
                              hipStream_t stream) {
    const float* x     = (const float*)d_in[0];
    const float* in_g  = (const float*)d_in[1];
    const float* in_b  = (const float*)d_in[2];
    const float* mid_g = (const float*)d_in[3];
    const float* mid_b = (const float*)d_in[4];
    const float* out_g = (const float*)d_in[5];
    const float* out_b = (const float*)d_in[6];
    const float* w_in  = (const float*)d_in[7];
    const float* w_out = (const float*)d_in[8];
    const float* slopes = (const float*)d_in[9];
    float* out = (float*)d_out;

    char* ws = (char*)d_ws;
    size_t off = 0;
    auto alloc = [&](size_t n) { char* p = ws + off; off += (n + 255) & ~(size_t)255; return p; };
    bf16* w_inT  = (bf16*)alloc((size_t)DPROJ_ * DM_ * 2);   // 14.7 MB
    bf16* w_outT = (bf16*)alloc((size_t)DM_ * DCAT * 2);     // 6.3 MB
    bf16* xs     = (bf16*)alloc((size_t)NTOK * DM_ * 2);     // 8.4 MB (reused as Vt)
    bf16* h      = (bf16*)alloc((size_t)NTOK * DPROJ_ * 2);  // 58.7 MB (reused: 2 contig f32 partials)
    bf16* A2     = (bf16*)alloc((size_t)NTOK * DCAT * 2);    // 25.2 MB
    bf16* Qp     = (bf16*)alloc((size_t)NTOK * DM_ * 2);     // 8.4 MB
    bf16* Kp     = (bf16*)alloc((size_t)NTOK * DM_ * 2);     // 8.4 MB
    bf16* Vn     = (bf16*)alloc((size_t)NTOK * DM_ * 2);     // 8.4 MB
    bf16* Vt = xs;            // xs dead after gemm1
    float* P = (float*)h;     // h dead after mid_ln_fused; gemm2 runs after attn (2x16.8MB fits)

    hipLaunchKernelGGL(prep, dim3(10240 + NTOK), dim3(256), 0, stream,
                       w_in, w_out, w_inT, w_outT, x, in_g, in_b, xs);
    hipLaunchKernelGGL(gemm1_zt, dim3(512), dim3(512), 0, stream, xs, w_inT, h);
    hipLaunchKernelGGL(mid_ln_fused, dim3(NTOK), dim3(256), 0, stream, h, mid_g, mid_b,
                       Qp, Kp, Vn, A2);
    hipLaunchKernelGGL(vt_pack, dim3(L_ / 32, DH_ / 32, B_ * HEADS_), dim3(256), 0, stream, Vn, Vt);
    hipLaunchKernelGGL(attn8, dim3(32, HEADS_, B_), dim3(256), 0, stream, Qp, Kp, Vt, slopes, A2);
    hipLaunchKernelGGL(gemm2_fr3, dim3(NTOK / 128, DM_ / 256, 2), dim3(512), 0, stream,
                       A2, w_outT, P);
    hipLaunchKernelGGL(out_ln2, dim3(NTOK), dim3(256), 0, stream, P, out_g, out_b, out);
}